// Round 6
// baseline (867.988 us; speedup 1.0000x reference)
//
#include <hip/hip_runtime.h>
#include <hip/hip_bf16.h>

#define BN_EPS 1e-5f

// Buckets of 512 nodes: bucket = dst >> 9. N=100K -> 196 buckets (<=256).
#define BUCK_SHIFT 9
#define NBUCK_MAX 256
#define PBLK 512   // blocks for hist/scatter passes

// ---------------------------------------------------------------------------
// generic exclusive scan (3 phases), n <= 512*256  (used for bucket counts)
__global__ __launch_bounds__(256) void scan_block(const int* __restrict__ in,
                                                  int* __restrict__ ex,
                                                  int* __restrict__ bsum, int n) {
    __shared__ int tmp[256];
    int tid = threadIdx.x;
    int i = blockIdx.x * 256 + tid;
    int v = (i < n) ? in[i] : 0;
    tmp[tid] = v;
    __syncthreads();
    for (int off = 1; off < 256; off <<= 1) {
        int t = (tid >= off) ? tmp[tid - off] : 0;
        __syncthreads();
        tmp[tid] += t;
        __syncthreads();
    }
    if (i < n) ex[i] = tmp[tid] - v;
    if (tid == 255) bsum[blockIdx.x] = tmp[255];
}

__global__ __launch_bounds__(512) void scan_bsum(int* __restrict__ bsum, int nb) {
    __shared__ int tmp[512];
    int tid = threadIdx.x;
    int v = (tid < nb) ? bsum[tid] : 0;
    tmp[tid] = v;
    __syncthreads();
    for (int off = 1; off < 512; off <<= 1) {
        int t = (tid >= off) ? tmp[tid - off] : 0;
        __syncthreads();
        tmp[tid] += t;
        __syncthreads();
    }
    if (tid < nb) bsum[tid] = tmp[tid] - v;
}

__global__ __launch_bounds__(256) void scan_add(int* __restrict__ ex,
                                                const int* __restrict__ bsum, int n) {
    int i = blockIdx.x * 256 + threadIdx.x;
    if (i < n) ex[i] += bsum[blockIdx.x];
}

// ---------------------------------------------------------------------------
// Phase A: per-block bucket histogram -> counts[bucket*P + blk]
__global__ __launch_bounds__(256) void bucket_hist(const int* __restrict__ dst,
                                                   int* __restrict__ counts,
                                                   int nE, int nbuck, int chunk) {
    __shared__ int h[NBUCK_MAX];
    const int blk = blockIdx.x, tid = threadIdx.x;
    for (int j = tid; j < nbuck; j += 256) h[j] = 0;
    __syncthreads();
    const int base = blk * chunk;
    const int end = min(base + chunk, nE);
    for (int i = base + tid; i < end; i += 256)
        atomicAdd(&h[dst[i] >> BUCK_SHIFT], 1);
    __syncthreads();
    for (int j = tid; j < nbuck; j += 256)
        counts[j * PBLK + blk] = h[j];
}

// Phase C: scatter edges into bucket-grouped ebuf using scanned offsets
__global__ __launch_bounds__(256) void bucket_scatter(const int* __restrict__ src,
                                                      const int* __restrict__ dst,
                                                      const int* __restrict__ offs,
                                                      int2* __restrict__ ebuf,
                                                      int nE, int nbuck, int chunk) {
    __shared__ int cur[NBUCK_MAX];
    const int blk = blockIdx.x, tid = threadIdx.x;
    for (int j = tid; j < nbuck; j += 256) cur[j] = offs[j * PBLK + blk];
    __syncthreads();
    const int base = blk * chunk;
    const int end = min(base + chunk, nE);
    for (int i = base + tid; i < end; i += 256) {
        int d = dst[i];
        int pos = atomicAdd(&cur[d >> BUCK_SHIFT], 1);
        ebuf[pos] = make_int2(src[i], d);
    }
}

// Phase D1 (fused): per-bucket degree histogram + dinv + row_start (intra-bucket
// scan seeded from bucket offset). One block per bucket.
__global__ __launch_bounds__(256) void bucket_degree_scan(const int2* __restrict__ ebuf,
                                                          const int* __restrict__ offs,
                                                          int* __restrict__ degI,
                                                          float* __restrict__ dinv,
                                                          int* __restrict__ row_start,
                                                          int nE, int nbuck, int n) {
    __shared__ int deg[512];
    __shared__ int tmp[256];
    __shared__ int s_low_total;
    const int b = blockIdx.x, tid = threadIdx.x;
    const int base = b << BUCK_SHIFT;
    for (int j = tid; j < 512; j += 256) deg[j] = 0;
    __syncthreads();
    const int s = offs[b * PBLK];
    const int e = (b + 1 < nbuck) ? offs[(b + 1) * PBLK] : nE;
    for (int i = s + tid; i < e; i += 256)
        atomicAdd(&deg[ebuf[i].y - base], 1);
    __syncthreads();

    // write degI + dinv (both halves)
    for (int j = tid; j < 512; j += 256) {
        int node = base + j;
        if (node < n) {
            int d = deg[j];
            degI[node] = d;
            dinv[node] = rsqrtf((float)d + 1.0f);
        }
    }

    // exclusive scan of deg[0..511]: two sequential 256-scans
    int v0 = deg[tid];
    tmp[tid] = v0;
    __syncthreads();
    for (int off = 1; off < 256; off <<= 1) {
        int t = (tid >= off) ? tmp[tid - off] : 0;
        __syncthreads();
        tmp[tid] += t;
        __syncthreads();
    }
    int ex_low = tmp[tid] - v0;
    if (tid == 255) s_low_total = tmp[255];
    __syncthreads();
    int low_total = s_low_total;
    int v1 = deg[256 + tid];
    __syncthreads();
    tmp[tid] = v1;
    __syncthreads();
    for (int off = 1; off < 256; off <<= 1) {
        int t = (tid >= off) ? tmp[tid - off] : 0;
        __syncthreads();
        tmp[tid] += t;
        __syncthreads();
    }
    int ex_high = tmp[tid] - v1 + low_total;

    if (base + tid < n) row_start[base + tid] = s + ex_low;
    if (base + 256 + tid < n) row_start[base + 256 + tid] = s + ex_high;
}

// Phase D2: fine CSR fill with LDS cursors (one block per bucket)
__global__ __launch_bounds__(256) void bucket_fill(const int2* __restrict__ ebuf,
                                                   const int* __restrict__ offs,
                                                   const int* __restrict__ row_start,
                                                   int* __restrict__ src_sorted,
                                                   int nE, int nbuck, int n) {
    __shared__ int cur[512];
    const int b = blockIdx.x, tid = threadIdx.x;
    const int base = b << BUCK_SHIFT;
    for (int j = tid; j < 512; j += 256) {
        int node = base + j;
        cur[j] = (node < n) ? row_start[node] : 0;
    }
    __syncthreads();
    const int s = offs[b * PBLK];
    const int e = (b + 1 < nbuck) ? offs[(b + 1) * PBLK] : nE;
    for (int i = s + tid; i < e; i += 256) {
        int2 ed = ebuf[i];
        int pos = atomicAdd(&cur[ed.y - base], 1);
        src_sorted[pos] = ed.x;
    }
}

// ---------------------------------------------------------------------------
// xs[i,c] = x[i,c] * dinv[i]
__global__ __launch_bounds__(256) void prescale36(const float* __restrict__ x,
                                                  const float* __restrict__ dinv,
                                                  float* __restrict__ xs, int n) {
    unsigned idx = blockIdx.x * 256u + threadIdx.x;
    if (idx >= (unsigned)n * 36u) return;
    xs[idx] = x[idx] * dinv[idx / 36u];
}

// ---------------------------------------------------------------------------
// Fused pull + GEMM(IN->128) + BN + ReLU [+ dinv output scale].
// Pull phase: 4 waves x 16 nodes fill the 64-row LDS tile directly from the
// CSR gather over pre-scaled features (feat_s = dinv .* h); then the standard
// register-tiled GEMM consumes the tile. Eliminates the A-buffer round trip.
template<int IN, bool SCALEOUT>
__global__ __launch_bounds__(256) void fused_pull_gemm(const float* __restrict__ feat_s,
                                                       const int* __restrict__ row_start,
                                                       const int* __restrict__ degI,
                                                       const int* __restrict__ src_sorted,
                                                       const float* __restrict__ dinv,
                                                       const float* __restrict__ W,
                                                       const float* __restrict__ bias,
                                                       const float* __restrict__ gg,
                                                       const float* __restrict__ bb,
                                                       const float* __restrict__ mm,
                                                       const float* __restrict__ vv,
                                                       float* __restrict__ out, int n) {
    constexpr int OUT = 128;
    constexpr int PAD = (IN == 36) ? 8 : 4;
    constexpr int LDW = IN + PAD;
    __shared__ float s_a[64][LDW];

    const int tid = threadIdx.x;
    const int wave = tid >> 6;
    const int lane = tid & 63;
    const int r0 = blockIdx.x * 64;

    // ---- pull phase: wave w fills rows w*16 .. w*16+15
    for (int t = 0; t < 16; t++) {
        const int r = wave * 16 + t;
        int node = __builtin_amdgcn_readfirstlane(r0 + r);
        if (node < n) {
            int e = row_start[node];
            const int re = e + degI[node];
            const float di = dinv[node];
            if constexpr (IN == 128) {
                const float2* __restrict__ f2 = (const float2*)feat_s;
                float2 acc = f2[(size_t)node * 64 + lane];
                for (; e + 3 < re; e += 4) {
                    int s0 = src_sorted[e], s1 = src_sorted[e + 1],
                        s2 = src_sorted[e + 2], s3 = src_sorted[e + 3];
                    float2 a0 = f2[(size_t)s0 * 64 + lane];
                    float2 a1 = f2[(size_t)s1 * 64 + lane];
                    float2 a2 = f2[(size_t)s2 * 64 + lane];
                    float2 a3 = f2[(size_t)s3 * 64 + lane];
                    acc.x += (a0.x + a1.x) + (a2.x + a3.x);
                    acc.y += (a0.y + a1.y) + (a2.y + a3.y);
                }
                for (; e < re; e++) {
                    float2 a = f2[(size_t)src_sorted[e] * 64 + lane];
                    acc.x += a.x;
                    acc.y += a.y;
                }
                s_a[r][2 * lane] = acc.x * di;
                s_a[r][2 * lane + 1] = acc.y * di;
            } else {
                float acc = 0.0f;
                if (lane < IN) acc = feat_s[(size_t)node * IN + lane];
                for (; e + 3 < re; e += 4) {
                    int s0 = src_sorted[e], s1 = src_sorted[e + 1],
                        s2 = src_sorted[e + 2], s3 = src_sorted[e + 3];
                    if (lane < IN) {
                        float a0 = feat_s[(size_t)s0 * IN + lane];
                        float a1 = feat_s[(size_t)s1 * IN + lane];
                        float a2 = feat_s[(size_t)s2 * IN + lane];
                        float a3 = feat_s[(size_t)s3 * IN + lane];
                        acc += (a0 + a1) + (a2 + a3);
                    }
                }
                for (; e < re; e++) {
                    int sidx = src_sorted[e];
                    if (lane < IN) acc += feat_s[(size_t)sidx * IN + lane];
                }
                if (lane < IN) s_a[r][lane] = acc * di;
            }
        } else {
            if constexpr (IN == 128) {
                s_a[r][2 * lane] = 0.0f;
                s_a[r][2 * lane + 1] = 0.0f;
            } else {
                if (lane < IN) s_a[r][lane] = 0.0f;
            }
        }
    }
    __syncthreads();

    // ---- gemm phase: CG=16 col-groups x RG=16 row-groups, TM=4 x TN=8
    constexpr int TN = 8;
    constexpr int CG = OUT / TN;   // 16
    constexpr int TM = 4;
    const int tx = tid % CG;
    const int ty = tid / CG;
    const int c0 = tx * TN;
    const int rr = ty * TM;

    float acc[TM][TN];
#pragma unroll
    for (int j = 0; j < TM; j++)
#pragma unroll
        for (int t = 0; t < TN; t++) acc[j][t] = 0.0f;

#pragma unroll 2
    for (int k = 0; k < IN; k += 4) {
        float4 a[TM];
#pragma unroll
        for (int j = 0; j < TM; j++) a[j] = *(const float4*)&s_a[rr + j][k];
#pragma unroll
        for (int kk = 0; kk < 4; kk++) {
            float4 wv0 = *(const float4*)(W + (size_t)(k + kk) * OUT + c0);
            float4 wv1 = *(const float4*)(W + (size_t)(k + kk) * OUT + c0 + 4);
#pragma unroll
            for (int j = 0; j < TM; j++) {
                float av = (kk == 0) ? a[j].x : (kk == 1) ? a[j].y : (kk == 2) ? a[j].z : a[j].w;
                acc[j][0] += av * wv0.x;
                acc[j][1] += av * wv0.y;
                acc[j][2] += av * wv0.z;
                acc[j][3] += av * wv0.w;
                acc[j][4] += av * wv1.x;
                acc[j][5] += av * wv1.y;
                acc[j][6] += av * wv1.z;
                acc[j][7] += av * wv1.w;
            }
        }
    }

    float scl[TN], sft[TN];
#pragma unroll
    for (int t = 0; t < TN; t++) {
        float s = gg[c0 + t] * rsqrtf(vv[c0 + t] + BN_EPS);
        scl[t] = s;
        sft[t] = bb[c0 + t] + (bias[c0 + t] - mm[c0 + t]) * s;
    }

#pragma unroll
    for (int j = 0; j < TM; j++) {
        int row = r0 + rr + j;
        if (row < n) {
            float ds = 1.0f;
            if constexpr (SCALEOUT) ds = dinv[row];
            float o[TN];
#pragma unroll
            for (int t = 0; t < TN; t++) {
                float val = fmaxf(acc[j][t] * scl[t] + sft[t], 0.0f);
                if constexpr (SCALEOUT) val *= ds;
                o[t] = val;
            }
            float* op = out + (size_t)row * OUT + c0;
            *(float4*)op = make_float4(o[0], o[1], o[2], o[3]);
            *(float4*)(op + 4) = make_float4(o[4], o[5], o[6], o[7]);
        }
    }
}

// ---------------------------------------------------------------------------
// Register-tiled fp32 GEMM (layer 2: 128 -> 64, raw, dinv-scaled output)
template<int IN, int OUT, bool BNRELU, bool SCALEOUT>
__global__ __launch_bounds__(256) void gemm_rt(const float* __restrict__ in,
                                               const float* __restrict__ W,
                                               const float* __restrict__ bias,
                                               const float* __restrict__ gg,
                                               const float* __restrict__ bb,
                                               const float* __restrict__ mm,
                                               const float* __restrict__ vv,
                                               const float* __restrict__ dscale,
                                               float* __restrict__ out, int n) {
    constexpr int BM = 64;
    constexpr int TN = 8;
    constexpr int CG = OUT / TN;
    constexpr int RG = 256 / CG;
    constexpr int TM = BM / RG;
    constexpr int PAD = (IN == 36) ? 8 : 4;
    constexpr int LDW = IN + PAD;
    __shared__ float s_a[BM][LDW];

    const int r0 = blockIdx.x * BM;
    const int tid = threadIdx.x;

    constexpr int T4 = BM * IN / 4;
    for (int i4 = tid; i4 < T4; i4 += 256) {
        int idx = i4 * 4;
        int r = idx / IN;
        int k = idx - r * IN;
        int row = r0 + r;
        float4 v = make_float4(0.f, 0.f, 0.f, 0.f);
        if (row < n) v = *(const float4*)(in + (size_t)row * IN + k);
        *(float4*)&s_a[r][k] = v;
    }
    __syncthreads();

    const int tx = tid % CG;
    const int ty = tid / CG;
    const int c0 = tx * TN;
    const int rr = ty * TM;

    float acc[TM][TN];
#pragma unroll
    for (int j = 0; j < TM; j++)
#pragma unroll
        for (int t = 0; t < TN; t++) acc[j][t] = 0.0f;

#pragma unroll 2
    for (int k = 0; k < IN; k += 4) {
        float4 a[TM];
#pragma unroll
        for (int j = 0; j < TM; j++) a[j] = *(const float4*)&s_a[rr + j][k];
#pragma unroll
        for (int kk = 0; kk < 4; kk++) {
            float4 wv0 = *(const float4*)(W + (size_t)(k + kk) * OUT + c0);
            float4 wv1 = *(const float4*)(W + (size_t)(k + kk) * OUT + c0 + 4);
#pragma unroll
            for (int j = 0; j < TM; j++) {
                float av = (kk == 0) ? a[j].x : (kk == 1) ? a[j].y : (kk == 2) ? a[j].z : a[j].w;
                acc[j][0] += av * wv0.x;
                acc[j][1] += av * wv0.y;
                acc[j][2] += av * wv0.z;
                acc[j][3] += av * wv0.w;
                acc[j][4] += av * wv1.x;
                acc[j][5] += av * wv1.y;
                acc[j][6] += av * wv1.z;
                acc[j][7] += av * wv1.w;
            }
        }
    }

    float scl[TN], sft[TN];
    if constexpr (BNRELU) {
#pragma unroll
        for (int t = 0; t < TN; t++) {
            float s = gg[c0 + t] * rsqrtf(vv[c0 + t] + BN_EPS);
            scl[t] = s;
            sft[t] = bb[c0 + t] + (bias[c0 + t] - mm[c0 + t]) * s;
        }
    }

#pragma unroll
    for (int j = 0; j < TM; j++) {
        int row = r0 + rr + j;
        if (row < n) {
            float ds = 1.0f;
            if constexpr (SCALEOUT) ds = dscale[row];
            float o[TN];
#pragma unroll
            for (int t = 0; t < TN; t++) {
                float val = acc[j][t];
                if constexpr (BNRELU) val = fmaxf(val * scl[t] + sft[t], 0.0f);
                if constexpr (SCALEOUT) val *= ds;
                o[t] = val;
            }
            float* op = out + (size_t)row * OUT + c0;
            *(float4*)op = make_float4(o[0], o[1], o[2], o[3]);
            *(float4*)(op + 4) = make_float4(o[4], o[5], o[6], o[7]);
        }
    }
}

// ---------------------------------------------------------------------------
// Fused layer-2 tail: wave-per-node 64-ch pull over pre-scaled gemm2 output,
// + bias + BN + ReLU + mean-pool atomic. No intermediate write.
__global__ __launch_bounds__(256) void agg_pull_pool(const float* __restrict__ feat_s,
                                                     const int* __restrict__ row_start,
                                                     const int* __restrict__ degI,
                                                     const int* __restrict__ src_sorted,
                                                     const float* __restrict__ dinv,
                                                     const float* __restrict__ bias,
                                                     const float* __restrict__ gg,
                                                     const float* __restrict__ bb,
                                                     const float* __restrict__ mm,
                                                     const float* __restrict__ vv,
                                                     const int* __restrict__ batch,
                                                     float* __restrict__ pool, int n) {
    int node = __builtin_amdgcn_readfirstlane((int)(blockIdx.x * 4 + (threadIdx.x >> 6)));
    if (node >= n) return;
    const int lane = threadIdx.x & 63;
    int e = row_start[node];
    const int re = e + degI[node];
    const float di = dinv[node];

    float acc = feat_s[(size_t)node * 64 + lane];
    for (; e + 3 < re; e += 4) {
        int s0 = src_sorted[e], s1 = src_sorted[e + 1],
            s2 = src_sorted[e + 2], s3 = src_sorted[e + 3];
        float a0 = feat_s[(size_t)s0 * 64 + lane];
        float a1 = feat_s[(size_t)s1 * 64 + lane];
        float a2 = feat_s[(size_t)s2 * 64 + lane];
        float a3 = feat_s[(size_t)s3 * 64 + lane];
        acc += (a0 + a1) + (a2 + a3);
    }
    for (; e < re; e++) {
        acc += feat_s[(size_t)src_sorted[e] * 64 + lane];
    }
    float h = acc * di + bias[lane];
    float scale = gg[lane] * rsqrtf(vv[lane] + BN_EPS);
    float val = fmaxf((h - mm[lane]) * scale + bb[lane], 0.0f);
    unsafeAtomicAdd(&pool[(size_t)batch[node] * 64 + lane], val);
}

// ---------------------------------------------------------------------------
// per-graph node count
__global__ __launch_bounds__(256) void count_kernel(const int* __restrict__ batch,
                                                    float* __restrict__ cnt, int n) {
    int i = blockIdx.x * 256 + threadIdx.x;
    if (i < n) unsafeAtomicAdd(&cnt[batch[i]], 1.0f);
}

// ---------------------------------------------------------------------------
// per-graph MLP head: 64 -> relu(128) -> relu(64) -> 2
__global__ __launch_bounds__(128) void fc_head_kernel(const float* __restrict__ pool,
                                                      const float* __restrict__ cnt,
                                                      const float* __restrict__ fw0,
                                                      const float* __restrict__ fb0,
                                                      const float* __restrict__ fw1,
                                                      const float* __restrict__ fb1,
                                                      const float* __restrict__ ow,
                                                      const float* __restrict__ ob,
                                                      float* __restrict__ out) {
    int g = blockIdx.x, tid = threadIdx.x;
    __shared__ float p[64], h1[128], h2[64];
    if (tid < 64) p[tid] = pool[g * 64 + tid] / fmaxf(cnt[g], 1.0f);
    __syncthreads();
    {
        float acc = fb0[tid];
        for (int k = 0; k < 64; k++) acc += p[k] * fw0[k * 128 + tid];
        h1[tid] = fmaxf(acc, 0.0f);
    }
    __syncthreads();
    if (tid < 64) {
        float acc = fb1[tid];
        for (int k = 0; k < 128; k++) acc += h1[k] * fw1[k * 64 + tid];
        h2[tid] = fmaxf(acc, 0.0f);
    }
    __syncthreads();
    if (tid < 2) {
        float acc = ob[tid];
        for (int k = 0; k < 64; k++) acc += h2[k] * ow[k * 2 + tid];
        out[g * 2 + tid] = acc;
    }
}

// ---------------------------------------------------------------------------
extern "C" void kernel_launch(void* const* d_in, const int* in_sizes, int n_in,
                              void* d_out, int out_size, void* d_ws, size_t ws_size,
                              hipStream_t stream) {
    const float* x     = (const float*)d_in[0];
    const int*   eidx  = (const int*)d_in[1];
    const int*   batch = (const int*)d_in[2];
    const float* w0 = (const float*)d_in[4];
    const float* b0 = (const float*)d_in[5];
    const float* g0 = (const float*)d_in[6];
    const float* be0 = (const float*)d_in[7];
    const float* m0 = (const float*)d_in[8];
    const float* v0 = (const float*)d_in[9];
    const float* w1 = (const float*)d_in[10];
    const float* b1 = (const float*)d_in[11];
    const float* g1 = (const float*)d_in[12];
    const float* be1 = (const float*)d_in[13];
    const float* m1 = (const float*)d_in[14];
    const float* v1 = (const float*)d_in[15];
    const float* w2 = (const float*)d_in[16];
    const float* b2 = (const float*)d_in[17];
    const float* g2 = (const float*)d_in[18];
    const float* be2 = (const float*)d_in[19];
    const float* m2 = (const float*)d_in[20];
    const float* v2 = (const float*)d_in[21];
    const float* fw0 = (const float*)d_in[22];
    const float* fb0 = (const float*)d_in[23];
    const float* fw1 = (const float*)d_in[24];
    const float* fb1 = (const float*)d_in[25];
    const float* ow = (const float*)d_in[26];
    const float* ob = (const float*)d_in[27];

    const int N = in_sizes[0] / 36;
    const int E = in_sizes[1] / 2;
    const int G = out_size / 2;
    const int* src = eidx;
    const int* dst = eidx + E;

    const int NB = (N + 255) / 256;
    const int nbuck = (N + 511) >> BUCK_SHIFT;    // 512-node buckets (<=256)
    const int chunk = (E + PBLK - 1) / PBLK;
    const int nCounts = nbuck * PBLK;
    const int NBc = (nCounts + 255) / 256;        // counts-scan blocks (<=512)

    // ---- workspace layout (ebuf first for 8B alignment; xs overlays ebuf,
    //      which is dead after bucket_fill)
    char* wsb = (char*)d_ws;
    int2*  ebuf       = (int2*)wsb;                      wsb += (size_t)E * 8;
    int*   counts     = (int*)wsb;                       wsb += (size_t)nCounts * 4;
    int*   degI       = (int*)wsb;                       wsb += (size_t)N * 4;
    int*   row_start  = (int*)wsb;                       wsb += (size_t)N * 4;
    int*   bsum       = (int*)wsb;                       wsb += 512 * 4;
    int*   src_sorted = (int*)wsb;                       wsb += (size_t)E * 4;
    float* dinv       = (float*)wsb;                     wsb += (size_t)N * 4;
    float* A          = (float*)wsb;                     wsb += (size_t)N * 128 * 4;
    float* B          = (float*)wsb;                     wsb += (size_t)N * 128 * 4;
    float* pool       = (float*)wsb;                     wsb += (size_t)G * 64 * 4;
    float* cnt        = (float*)wsb;
    float* xs         = (float*)ebuf;   // N*36 floats, overlays dead ebuf

    // ---- two-level counting sort -> bucket-grouped ebuf -> CSR (+deg/dinv)
    bucket_hist<<<PBLK, 256, 0, stream>>>(dst, counts, E, nbuck, chunk);
    scan_block<<<NBc, 256, 0, stream>>>(counts, counts, bsum, nCounts);
    scan_bsum<<<1, 512, 0, stream>>>(bsum, NBc);
    scan_add<<<NBc, 256, 0, stream>>>(counts, bsum, nCounts);
    bucket_scatter<<<PBLK, 256, 0, stream>>>(src, dst, counts, ebuf, E, nbuck, chunk);
    bucket_degree_scan<<<nbuck, 256, 0, stream>>>(ebuf, counts, degI, dinv, row_start, E, nbuck, N);
    bucket_fill<<<nbuck, 256, 0, stream>>>(ebuf, counts, row_start, src_sorted, E, nbuck, N);

    const int NW = (N + 3) / 4;     // wave-per-node grid (4 waves/block)
    const int NG = (N + 63) / 64;   // 64-row tile grid

    // ---- layer 0: xs = dinv.*x, fused pull36+GEMM(36->128)+BN+ReLU, x dinv -> B
    {
        unsigned total = (unsigned)N * 36u;
        prescale36<<<(total + 255) / 256, 256, 0, stream>>>(x, dinv, xs, N);
    }
    fused_pull_gemm<36, true><<<NG, 256, 0, stream>>>(
        xs, row_start, degI, src_sorted, dinv, w0, b0, g0, be0, m0, v0, B, N);

    // ---- layer 1: fused pull128+GEMM(128->128)+BN+ReLU (B -> A)
    fused_pull_gemm<128, false><<<NG, 256, 0, stream>>>(
        B, row_start, degI, src_sorted, dinv, w1, b1, g1, be1, m1, v1, A, N);

    // ---- layer 2: GEMM 128->64 raw, output scaled by dinv (A -> B)
    gemm_rt<128, 64, false, true><<<NG, 256, 0, stream>>>(
        A, w2, nullptr, nullptr, nullptr, nullptr, nullptr, dinv, B, N);

    // ---- fused pull64 + bias + BN + ReLU + mean-pool (B -> pool)
    hipMemsetAsync(pool, 0, (size_t)G * 64 * 4, stream);
    hipMemsetAsync(cnt, 0, (size_t)G * 4, stream);
    count_kernel<<<NB, 256, 0, stream>>>(batch, cnt, N);
    agg_pull_pool<<<NW, 256, 0, stream>>>(
        B, row_start, degI, src_sorted, dinv, b2, g2, be2, m2, v2, batch, pool, N);

    // ---- MLP head
    fc_head_kernel<<<G, 128, 0, stream>>>(pool, cnt, fw0, fb0, fw1, fb1, ow, ob, (float*)d_out);
}

// Round 7
// 831.834 us; speedup vs baseline: 1.0435x; 1.0435x over previous
//
#include <hip/hip_runtime.h>
#include <hip/hip_bf16.h>

#define BN_EPS 1e-5f

// Buckets of 512 nodes: bucket = dst >> 9. N=100K -> 196 buckets (<=256).
#define BUCK_SHIFT 9
#define NBUCK_MAX 256
#define PBLK 512   // blocks for hist/scatter passes

// ---------------------------------------------------------------------------
// generic exclusive scan (3 phases), used for bucket counts
__global__ __launch_bounds__(256) void scan_block(const int* __restrict__ in,
                                                  int* __restrict__ ex,
                                                  int* __restrict__ bsum, int n) {
    __shared__ int tmp[256];
    int tid = threadIdx.x;
    int i = blockIdx.x * 256 + tid;
    int v = (i < n) ? in[i] : 0;
    tmp[tid] = v;
    __syncthreads();
    for (int off = 1; off < 256; off <<= 1) {
        int t = (tid >= off) ? tmp[tid - off] : 0;
        __syncthreads();
        tmp[tid] += t;
        __syncthreads();
    }
    if (i < n) ex[i] = tmp[tid] - v;
    if (tid == 255) bsum[blockIdx.x] = tmp[255];
}

__global__ __launch_bounds__(512) void scan_bsum(int* __restrict__ bsum, int nb) {
    __shared__ int tmp[512];
    int tid = threadIdx.x;
    int v = (tid < nb) ? bsum[tid] : 0;
    tmp[tid] = v;
    __syncthreads();
    for (int off = 1; off < 512; off <<= 1) {
        int t = (tid >= off) ? tmp[tid - off] : 0;
        __syncthreads();
        tmp[tid] += t;
        __syncthreads();
    }
    if (tid < nb) bsum[tid] = tmp[tid] - v;
}

__global__ __launch_bounds__(256) void scan_add(int* __restrict__ ex,
                                                const int* __restrict__ bsum, int n) {
    int i = blockIdx.x * 256 + threadIdx.x;
    if (i < n) ex[i] += bsum[blockIdx.x];
}

// ---------------------------------------------------------------------------
// Phase A: per-block bucket histogram -> counts[bucket*P + blk]
__global__ __launch_bounds__(256) void bucket_hist(const int* __restrict__ dst,
                                                   int* __restrict__ counts,
                                                   int nE, int nbuck, int chunk) {
    __shared__ int h[NBUCK_MAX];
    const int blk = blockIdx.x, tid = threadIdx.x;
    for (int j = tid; j < nbuck; j += 256) h[j] = 0;
    __syncthreads();
    const int base = blk * chunk;
    const int end = min(base + chunk, nE);
    for (int i = base + tid; i < end; i += 256)
        atomicAdd(&h[dst[i] >> BUCK_SHIFT], 1);
    __syncthreads();
    for (int j = tid; j < nbuck; j += 256)
        counts[j * PBLK + blk] = h[j];
}

// Phase C: scatter edges into bucket-grouped ebuf using scanned offsets
__global__ __launch_bounds__(256) void bucket_scatter(const int* __restrict__ src,
                                                      const int* __restrict__ dst,
                                                      const int* __restrict__ offs,
                                                      int2* __restrict__ ebuf,
                                                      int nE, int nbuck, int chunk) {
    __shared__ int cur[NBUCK_MAX];
    const int blk = blockIdx.x, tid = threadIdx.x;
    for (int j = tid; j < nbuck; j += 256) cur[j] = offs[j * PBLK + blk];
    __syncthreads();
    const int base = blk * chunk;
    const int end = min(base + chunk, nE);
    for (int i = base + tid; i < end; i += 256) {
        int d = dst[i];
        int pos = atomicAdd(&cur[d >> BUCK_SHIFT], 1);
        ebuf[pos] = make_int2(src[i], d);
    }
}

// Phase D1 (fused): per-bucket degree histogram + dinv + row_start. One block per bucket.
__global__ __launch_bounds__(256) void bucket_degree_scan(const int2* __restrict__ ebuf,
                                                          const int* __restrict__ offs,
                                                          int* __restrict__ degI,
                                                          float* __restrict__ dinv,
                                                          int* __restrict__ row_start,
                                                          int nE, int nbuck, int n) {
    __shared__ int deg[512];
    __shared__ int tmp[256];
    __shared__ int s_low_total;
    const int b = blockIdx.x, tid = threadIdx.x;
    const int base = b << BUCK_SHIFT;
    for (int j = tid; j < 512; j += 256) deg[j] = 0;
    __syncthreads();
    const int s = offs[b * PBLK];
    const int e = (b + 1 < nbuck) ? offs[(b + 1) * PBLK] : nE;
    for (int i = s + tid; i < e; i += 256)
        atomicAdd(&deg[ebuf[i].y - base], 1);
    __syncthreads();

    for (int j = tid; j < 512; j += 256) {
        int node = base + j;
        if (node < n) {
            int d = deg[j];
            degI[node] = d;
            dinv[node] = rsqrtf((float)d + 1.0f);
        }
    }

    int v0 = deg[tid];
    tmp[tid] = v0;
    __syncthreads();
    for (int off = 1; off < 256; off <<= 1) {
        int t = (tid >= off) ? tmp[tid - off] : 0;
        __syncthreads();
        tmp[tid] += t;
        __syncthreads();
    }
    int ex_low = tmp[tid] - v0;
    if (tid == 255) s_low_total = tmp[255];
    __syncthreads();
    int low_total = s_low_total;
    int v1 = deg[256 + tid];
    __syncthreads();
    tmp[tid] = v1;
    __syncthreads();
    for (int off = 1; off < 256; off <<= 1) {
        int t = (tid >= off) ? tmp[tid - off] : 0;
        __syncthreads();
        tmp[tid] += t;
        __syncthreads();
    }
    int ex_high = tmp[tid] - v1 + low_total;

    if (base + tid < n) row_start[base + tid] = s + ex_low;
    if (base + 256 + tid < n) row_start[base + 256 + tid] = s + ex_high;
}

// Phase D2: fine CSR fill with LDS cursors (one block per bucket)
__global__ __launch_bounds__(256) void bucket_fill(const int2* __restrict__ ebuf,
                                                   const int* __restrict__ offs,
                                                   const int* __restrict__ row_start,
                                                   int* __restrict__ src_sorted,
                                                   int nE, int nbuck, int n) {
    __shared__ int cur[512];
    const int b = blockIdx.x, tid = threadIdx.x;
    const int base = b << BUCK_SHIFT;
    for (int j = tid; j < 512; j += 256) {
        int node = base + j;
        cur[j] = (node < n) ? row_start[node] : 0;
    }
    __syncthreads();
    const int s = offs[b * PBLK];
    const int e = (b + 1 < nbuck) ? offs[(b + 1) * PBLK] : nE;
    for (int i = s + tid; i < e; i += 256) {
        int2 ed = ebuf[i];
        int pos = atomicAdd(&cur[ed.y - base], 1);
        src_sorted[pos] = ed.x;
    }
}

// ---------------------------------------------------------------------------
// xs[i,c] = x[i,c] * dinv[i]
__global__ __launch_bounds__(256) void prescale36(const float* __restrict__ x,
                                                  const float* __restrict__ dinv,
                                                  float* __restrict__ xs, int n) {
    unsigned idx = blockIdx.x * 256u + threadIdx.x;
    if (idx >= (unsigned)n * 36u) return;
    xs[idx] = x[idx] * dinv[idx / 36u];
}

// wave-per-node pull over pre-scaled 36-ch features
__global__ __launch_bounds__(256) void agg_pull36w(const float* __restrict__ xs,
                                                   const int* __restrict__ row_start,
                                                   const int* __restrict__ degI,
                                                   const int* __restrict__ src_sorted,
                                                   const float* __restrict__ dinv,
                                                   float* __restrict__ out, int n) {
    int node = __builtin_amdgcn_readfirstlane((int)(blockIdx.x * 4 + (threadIdx.x >> 6)));
    if (node >= n) return;
    const int lane = threadIdx.x & 63;
    int e = row_start[node];
    const int re = e + degI[node];
    const float di = dinv[node];
    float acc = 0.0f;
    if (lane < 36) acc = xs[(size_t)node * 36 + lane];
    for (; e + 3 < re; e += 4) {
        int s0 = src_sorted[e], s1 = src_sorted[e + 1],
            s2 = src_sorted[e + 2], s3 = src_sorted[e + 3];
        if (lane < 36) {
            float a0 = xs[(size_t)s0 * 36 + lane];
            float a1 = xs[(size_t)s1 * 36 + lane];
            float a2 = xs[(size_t)s2 * 36 + lane];
            float a3 = xs[(size_t)s3 * 36 + lane];
            acc += (a0 + a1) + (a2 + a3);
        }
    }
    for (; e < re; e++) {
        int s = src_sorted[e];
        if (lane < 36) acc += xs[(size_t)s * 36 + lane];
    }
    if (lane < 36) out[(size_t)node * 36 + lane] = acc * di;
}

// ---------------------------------------------------------------------------
// wave-per-node pull over PRE-SCALED 128-ch features (float2/lane)
__global__ __launch_bounds__(256) void agg_pull_wave2(const float* __restrict__ feat_s,
                                                      const int* __restrict__ row_start,
                                                      const int* __restrict__ degI,
                                                      const int* __restrict__ src_sorted,
                                                      const float* __restrict__ dinv,
                                                      float* __restrict__ out, int n) {
    int node = __builtin_amdgcn_readfirstlane((int)(blockIdx.x * 4 + (threadIdx.x >> 6)));
    if (node >= n) return;
    const int lane = threadIdx.x & 63;
    int e = row_start[node];
    const int re = e + degI[node];
    const float di = dinv[node];

    const float2* __restrict__ f2 = (const float2*)feat_s;
    float2 acc = f2[(size_t)node * 64 + lane];
    for (; e + 3 < re; e += 4) {
        int s0 = src_sorted[e], s1 = src_sorted[e + 1],
            s2 = src_sorted[e + 2], s3 = src_sorted[e + 3];
        float2 a0 = f2[(size_t)s0 * 64 + lane];
        float2 a1 = f2[(size_t)s1 * 64 + lane];
        float2 a2 = f2[(size_t)s2 * 64 + lane];
        float2 a3 = f2[(size_t)s3 * 64 + lane];
        acc.x += (a0.x + a1.x) + (a2.x + a3.x);
        acc.y += (a0.y + a1.y) + (a2.y + a3.y);
    }
    for (; e < re; e++) {
        int s = src_sorted[e];
        float2 a = f2[(size_t)s * 64 + lane];
        acc.x += a.x;
        acc.y += a.y;
    }
    float2 o;
    o.x = acc.x * di;
    o.y = acc.y * di;
    ((float2*)out)[(size_t)node * 64 + lane] = o;
}

// ---------------------------------------------------------------------------
// Register-tiled fp32 GEMM: 64-row tile in LDS, each thread computes TM x 8.
template<int IN, int OUT, bool BNRELU, bool SCALEOUT>
__global__ __launch_bounds__(256) void gemm_rt(const float* __restrict__ in,
                                               const float* __restrict__ W,
                                               const float* __restrict__ bias,
                                               const float* __restrict__ gg,
                                               const float* __restrict__ bb,
                                               const float* __restrict__ mm,
                                               const float* __restrict__ vv,
                                               const float* __restrict__ dscale,
                                               float* __restrict__ out, int n) {
    constexpr int BM = 64;
    constexpr int TN = 8;
    constexpr int CG = OUT / TN;
    constexpr int RG = 256 / CG;
    constexpr int TM = BM / RG;
    constexpr int PAD = (IN == 36) ? 8 : 4;
    constexpr int LDW = IN + PAD;
    __shared__ float s_a[BM][LDW];

    const int r0 = blockIdx.x * BM;
    const int tid = threadIdx.x;

    constexpr int T4 = BM * IN / 4;
    for (int i4 = tid; i4 < T4; i4 += 256) {
        int idx = i4 * 4;
        int r = idx / IN;
        int k = idx - r * IN;
        int row = r0 + r;
        float4 v = make_float4(0.f, 0.f, 0.f, 0.f);
        if (row < n) v = *(const float4*)(in + (size_t)row * IN + k);
        *(float4*)&s_a[r][k] = v;
    }
    __syncthreads();

    const int tx = tid % CG;
    const int ty = tid / CG;
    const int c0 = tx * TN;
    const int rr = ty * TM;

    float acc[TM][TN];
#pragma unroll
    for (int j = 0; j < TM; j++)
#pragma unroll
        for (int t = 0; t < TN; t++) acc[j][t] = 0.0f;

#pragma unroll 2
    for (int k = 0; k < IN; k += 4) {
        float4 a[TM];
#pragma unroll
        for (int j = 0; j < TM; j++) a[j] = *(const float4*)&s_a[rr + j][k];
#pragma unroll
        for (int kk = 0; kk < 4; kk++) {
            float4 wv0 = *(const float4*)(W + (size_t)(k + kk) * OUT + c0);
            float4 wv1 = *(const float4*)(W + (size_t)(k + kk) * OUT + c0 + 4);
#pragma unroll
            for (int j = 0; j < TM; j++) {
                float av = (kk == 0) ? a[j].x : (kk == 1) ? a[j].y : (kk == 2) ? a[j].z : a[j].w;
                acc[j][0] += av * wv0.x;
                acc[j][1] += av * wv0.y;
                acc[j][2] += av * wv0.z;
                acc[j][3] += av * wv0.w;
                acc[j][4] += av * wv1.x;
                acc[j][5] += av * wv1.y;
                acc[j][6] += av * wv1.z;
                acc[j][7] += av * wv1.w;
            }
        }
    }

    float scl[TN], sft[TN];
    if constexpr (BNRELU) {
#pragma unroll
        for (int t = 0; t < TN; t++) {
            float s = gg[c0 + t] * rsqrtf(vv[c0 + t] + BN_EPS);
            scl[t] = s;
            sft[t] = bb[c0 + t] + (bias[c0 + t] - mm[c0 + t]) * s;
        }
    }

#pragma unroll
    for (int j = 0; j < TM; j++) {
        int row = r0 + rr + j;
        if (row < n) {
            float ds = 1.0f;
            if constexpr (SCALEOUT) ds = dscale[row];
            float o[TN];
#pragma unroll
            for (int t = 0; t < TN; t++) {
                float val = acc[j][t];
                if constexpr (BNRELU) val = fmaxf(val * scl[t] + sft[t], 0.0f);
                if constexpr (SCALEOUT) val *= ds;
                o[t] = val;
            }
            float* op = out + (size_t)row * OUT + c0;
            *(float4*)op = make_float4(o[0], o[1], o[2], o[3]);
            *(float4*)(op + 4) = make_float4(o[4], o[5], o[6], o[7]);
        }
    }
}

// ---------------------------------------------------------------------------
// Fused layer-2 tail: wave-per-node 64-ch pull over pre-scaled gemm2 output,
// + bias + BN + ReLU + mean-pool atomic.
__global__ __launch_bounds__(256) void agg_pull_pool(const float* __restrict__ feat_s,
                                                     const int* __restrict__ row_start,
                                                     const int* __restrict__ degI,
                                                     const int* __restrict__ src_sorted,
                                                     const float* __restrict__ dinv,
                                                     const float* __restrict__ bias,
                                                     const float* __restrict__ gg,
                                                     const float* __restrict__ bb,
                                                     const float* __restrict__ mm,
                                                     const float* __restrict__ vv,
                                                     const int* __restrict__ batch,
                                                     float* __restrict__ pool, int n) {
    int node = __builtin_amdgcn_readfirstlane((int)(blockIdx.x * 4 + (threadIdx.x >> 6)));
    if (node >= n) return;
    const int lane = threadIdx.x & 63;
    int e = row_start[node];
    const int re = e + degI[node];
    const float di = dinv[node];

    float acc = feat_s[(size_t)node * 64 + lane];
    for (; e + 3 < re; e += 4) {
        int s0 = src_sorted[e], s1 = src_sorted[e + 1],
            s2 = src_sorted[e + 2], s3 = src_sorted[e + 3];
        float a0 = feat_s[(size_t)s0 * 64 + lane];
        float a1 = feat_s[(size_t)s1 * 64 + lane];
        float a2 = feat_s[(size_t)s2 * 64 + lane];
        float a3 = feat_s[(size_t)s3 * 64 + lane];
        acc += (a0 + a1) + (a2 + a3);
    }
    for (; e < re; e++) {
        acc += feat_s[(size_t)src_sorted[e] * 64 + lane];
    }
    float h = acc * di + bias[lane];
    float scale = gg[lane] * rsqrtf(vv[lane] + BN_EPS);
    float val = fmaxf((h - mm[lane]) * scale + bb[lane], 0.0f);
    unsafeAtomicAdd(&pool[(size_t)batch[node] * 64 + lane], val);
}

// ---------------------------------------------------------------------------
// per-graph node count
__global__ __launch_bounds__(256) void count_kernel(const int* __restrict__ batch,
                                                    float* __restrict__ cnt, int n) {
    int i = blockIdx.x * 256 + threadIdx.x;
    if (i < n) unsafeAtomicAdd(&cnt[batch[i]], 1.0f);
}

// ---------------------------------------------------------------------------
// per-graph MLP head: 64 -> relu(128) -> relu(64) -> 2
__global__ __launch_bounds__(128) void fc_head_kernel(const float* __restrict__ pool,
                                                      const float* __restrict__ cnt,
                                                      const float* __restrict__ fw0,
                                                      const float* __restrict__ fb0,
                                                      const float* __restrict__ fw1,
                                                      const float* __restrict__ fb1,
                                                      const float* __restrict__ ow,
                                                      const float* __restrict__ ob,
                                                      float* __restrict__ out) {
    int g = blockIdx.x, tid = threadIdx.x;
    __shared__ float p[64], h1[128], h2[64];
    if (tid < 64) p[tid] = pool[g * 64 + tid] / fmaxf(cnt[g], 1.0f);
    __syncthreads();
    {
        float acc = fb0[tid];
        for (int k = 0; k < 64; k++) acc += p[k] * fw0[k * 128 + tid];
        h1[tid] = fmaxf(acc, 0.0f);
    }
    __syncthreads();
    if (tid < 64) {
        float acc = fb1[tid];
        for (int k = 0; k < 128; k++) acc += h1[k] * fw1[k * 64 + tid];
        h2[tid] = fmaxf(acc, 0.0f);
    }
    __syncthreads();
    if (tid < 2) {
        float acc = ob[tid];
        for (int k = 0; k < 64; k++) acc += h2[k] * ow[k * 2 + tid];
        out[g * 2 + tid] = acc;
    }
}

// ---------------------------------------------------------------------------
extern "C" void kernel_launch(void* const* d_in, const int* in_sizes, int n_in,
                              void* d_out, int out_size, void* d_ws, size_t ws_size,
                              hipStream_t stream) {
    const float* x     = (const float*)d_in[0];
    const int*   eidx  = (const int*)d_in[1];
    const int*   batch = (const int*)d_in[2];
    const float* w0 = (const float*)d_in[4];
    const float* b0 = (const float*)d_in[5];
    const float* g0 = (const float*)d_in[6];
    const float* be0 = (const float*)d_in[7];
    const float* m0 = (const float*)d_in[8];
    const float* v0 = (const float*)d_in[9];
    const float* w1 = (const float*)d_in[10];
    const float* b1 = (const float*)d_in[11];
    const float* g1 = (const float*)d_in[12];
    const float* be1 = (const float*)d_in[13];
    const float* m1 = (const float*)d_in[14];
    const float* v1 = (const float*)d_in[15];
    const float* w2 = (const float*)d_in[16];
    const float* b2 = (const float*)d_in[17];
    const float* g2 = (const float*)d_in[18];
    const float* be2 = (const float*)d_in[19];
    const float* m2 = (const float*)d_in[20];
    const float* v2 = (const float*)d_in[21];
    const float* fw0 = (const float*)d_in[22];
    const float* fb0 = (const float*)d_in[23];
    const float* fw1 = (const float*)d_in[24];
    const float* fb1 = (const float*)d_in[25];
    const float* ow = (const float*)d_in[26];
    const float* ob = (const float*)d_in[27];

    const int N = in_sizes[0] / 36;
    const int E = in_sizes[1] / 2;
    const int G = out_size / 2;
    const int* src = eidx;
    const int* dst = eidx + E;

    const int NB = (N + 255) / 256;
    const int nbuck = (N + 511) >> BUCK_SHIFT;    // 512-node buckets (<=256)
    const int chunk = (E + PBLK - 1) / PBLK;
    const int nCounts = nbuck * PBLK;
    const int NBc = (nCounts + 255) / 256;        // counts-scan blocks (<=512)

    // ---- workspace layout (ebuf first for 8B alignment; xs overlays ebuf,
    //      which is dead after bucket_fill)
    char* wsb = (char*)d_ws;
    int2*  ebuf       = (int2*)wsb;                      wsb += (size_t)E * 8;
    int*   counts     = (int*)wsb;                       wsb += (size_t)nCounts * 4;
    int*   degI       = (int*)wsb;                       wsb += (size_t)N * 4;
    int*   row_start  = (int*)wsb;                       wsb += (size_t)N * 4;
    int*   bsum       = (int*)wsb;                       wsb += 512 * 4;
    int*   src_sorted = (int*)wsb;                       wsb += (size_t)E * 4;
    float* dinv       = (float*)wsb;                     wsb += (size_t)N * 4;
    float* A          = (float*)wsb;                     wsb += (size_t)N * 128 * 4;
    float* B          = (float*)wsb;                     wsb += (size_t)N * 128 * 4;
    float* pool       = (float*)wsb;                     wsb += (size_t)G * 64 * 4;
    float* cnt        = (float*)wsb;
    float* xs         = (float*)ebuf;   // N*36 floats, overlays dead ebuf

    // ---- two-level counting sort -> bucket-grouped ebuf -> CSR (+deg/dinv)
    bucket_hist<<<PBLK, 256, 0, stream>>>(dst, counts, E, nbuck, chunk);
    scan_block<<<NBc, 256, 0, stream>>>(counts, counts, bsum, nCounts);
    scan_bsum<<<1, 512, 0, stream>>>(bsum, NBc);
    scan_add<<<NBc, 256, 0, stream>>>(counts, bsum, nCounts);
    bucket_scatter<<<PBLK, 256, 0, stream>>>(src, dst, counts, ebuf, E, nbuck, chunk);
    bucket_degree_scan<<<nbuck, 256, 0, stream>>>(ebuf, counts, degI, dinv, row_start, E, nbuck, N);
    bucket_fill<<<nbuck, 256, 0, stream>>>(ebuf, counts, row_start, src_sorted, E, nbuck, N);

    const int NW = (N + 3) / 4;     // wave-per-node grid (4 waves/block)
    const int NG = (N + 63) / 64;   // 64-row tile grid

    // ---- layer 0: xs = dinv.*x, pull36 (xs -> A), GEMM 36->128 +BN+ReLU x dinv (A -> B)
    {
        unsigned total = (unsigned)N * 36u;
        prescale36<<<(total + 255) / 256, 256, 0, stream>>>(x, dinv, xs, N);
    }
    agg_pull36w<<<NW, 256, 0, stream>>>(xs, row_start, degI, src_sorted, dinv, A, N);
    gemm_rt<36, 128, true, true><<<NG, 256, 0, stream>>>(A, w0, b0, g0, be0, m0, v0, dinv, B, N);

    // ---- layer 1: pull 128-ch scaled (B -> A), GEMM 128->128 +BN+ReLU (A -> B)
    agg_pull_wave2<<<NW, 256, 0, stream>>>(B, row_start, degI, src_sorted, dinv, A, N);
    gemm_rt<128, 128, true, false><<<NG, 256, 0, stream>>>(A, w1, b1, g1, be1, m1, v1, nullptr, B, N);

    // ---- layer 2: GEMM 128->64 raw, output scaled by dinv (B -> A)
    gemm_rt<128, 64, false, true><<<NG, 256, 0, stream>>>(
        B, w2, nullptr, nullptr, nullptr, nullptr, nullptr, dinv, A, N);

    // ---- fused pull64 + bias + BN + ReLU + mean-pool (A -> pool)
    hipMemsetAsync(pool, 0, (size_t)G * 64 * 4, stream);
    hipMemsetAsync(cnt, 0, (size_t)G * 4, stream);
    count_kernel<<<NB, 256, 0, stream>>>(batch, cnt, N);
    agg_pull_pool<<<NW, 256, 0, stream>>>(
        A, row_start, degI, src_sorted, dinv, b2, g2, be2, m2, v2, batch, pool, N);

    // ---- MLP head
    fc_head_kernel<<<G, 128, 0, stream>>>(pool, cnt, fw0, fb0, fw1, fb1, ow, ob, (float*)d_out);
}